// Round 14
// baseline (222.090 us; speedup 1.0000x reference)
//
#include <hip/hip_runtime.h>

// B=32, C=64, H=W=112. Per-sample 3x3 convs via bf16 MFMA implicit GEMM.
// Image format: per-sample ZERO-PADDED half-planes [b][half(ci32)][slot][32ci],
// slot = POFF + y*113 + x; col 112 of each row = shared zero border; 128 zero
// slots lead, 273 trail. PIXEL-tiled: pixel p in [0,12544), slot = p + p/112.
// Conv block (256 thr = 4 waves): tile = 256 px. LDS = one weight ci-half
// (36.9KB) + one B ci-half window (512 slots, 32.8KB) = 69.6KB -> 2 blocks/CU.
// Phase 1's W+B are prefetched to REGISTERS before phase 0's k-loop (T14
// async-stage split) and ds_written after the mid-barrier. k-loop = pure
// {4 ds_read A, 4 ds_read B, 16 MFMA} per tap. Wave = 64co x 64px (acc[4][4]).
// BN1 affine+ReLU fused into conv2 staging; BN batch stats fused in epilogue.
#define HW   112
#define HW2  12544
#define CH   64
#define NB   32
#define PRW  113
#define NP   12655          // interior slots per sample
#define POFF 128
#define PS   13056          // slots per half-plane per sample
#define NPC  (NB*HW2)
#define TPX  256            // pixels per conv tile

using u16 = unsigned short;
typedef __attribute__((ext_vector_type(8))) short bf16x8;   // 8 bf16 = 4 VGPRs
typedef __attribute__((ext_vector_type(4))) float f32x4;

__device__ __forceinline__ float b2f(u16 u) {
    union { unsigned int i; float f; } c;
    c.i = ((unsigned int)u) << 16;
    return c.f;
}
__device__ __forceinline__ u16 f2b(float f) {
    union { float f; unsigned int i; } c;
    c.f = f;
    unsigned int x = c.i;
    x += 0x7fffu + ((x >> 16) & 1u);   // RNE
    return (u16)(x >> 16);
}

// 9 taps over one ci-half: 4 A ds_reads + 4 B ds_reads + 16 MFMA per tap.
__device__ __forceinline__ void kloop(const u16* __restrict__ wl,
                                      const u16* __restrict__ bt,
                                      const int* lsf, int kg, int px,
                                      f32x4 (&acc)[4][4])
{
#pragma unroll
    for (int tap = 0; tap < 9; ++tap) {
        const int off = (tap / 3 - 1) * PRW + (tap % 3 - 1);
        bf16x8 Af[4];
#pragma unroll
        for (int m = 0; m < 4; ++m)
            Af[m] = *(const bf16x8*)(wl + tap * 2048 + kg * 512 + (m * 16 + px) * 8);
#pragma unroll
        for (int f = 0; f < 4; ++f) {
            bf16x8 Bf = *(const bf16x8*)(bt + (lsf[f] + off) * 32 + kg * 8);
#pragma unroll
            for (int m = 0; m < 4; ++m)
                acc[f][m] = __builtin_amdgcn_mfma_f32_16x16x32_bf16(Af[m], Bf, acc[f][m], 0, 0, 0);
        }
    }
}

// MODE 0: conv1 (input = padded x half-planes, output = padded y1 half-planes)
// MODE 1: conv2 (input = padded y1 half-planes, BN1 affine+ReLU fused into
//                staging; output = COMPACT y2 [b][pix12544][64])
// wt: bf16 [b][half][tap][kq][co][8ci].
template<int MODE>
__global__ __launch_bounds__(256, 2)
void conv_mfma(const u16* __restrict__ img, const u16* __restrict__ wt,
               u16* __restrict__ outp, float* __restrict__ sums,
               const float* __restrict__ psums, const float* __restrict__ gamma,
               const float* __restrict__ beta)
{
    __shared__ u16 wl[18432];            // 36864 B: [tap][kq][co][8ci] one half
    __shared__ u16 bt[16384];            // 32768 B: 512 slots x 32ci
    // XCD swizzle: 1568 = 8 x 196 -> consecutive ids on one XCD share samples.
    const int bid = (int)blockIdx.x;
    const int sid = (bid & 7) * 196 + (bid >> 3);
    const int b = sid / 49, tile = sid - b * 49;
    const int p0 = tile * TPX;
    const int w0 = p0 + p0 / HW - 114;   // staged window start (slot space)
    const int tid = threadIdx.x;
    const int lane = tid & 63, wave = tid >> 6;
    const int px = lane & 15, kg = lane >> 4;
    const u16* wtb = wt + (size_t)b * 36864;

    // ---- BN1 params for MODE1 staging (q = tid&3 loop-invariant) ----
    float sc0[8], bi0[8], sc1[8], bi1[8];
    if (MODE == 1) {
        const int q = tid & 3;
#pragma unroll
        for (int e = 0; e < 8; ++e) {
            int c0 = q * 8 + e, c1 = 32 + q * 8 + e;
            float m0 = psums[c0] * (1.f / NPC), m1 = psums[c1] * (1.f / NPC);
            float v0 = psums[64 + c0] * (1.f / NPC) - m0 * m0;
            float v1 = psums[64 + c1] * (1.f / NPC) - m1 * m1;
            sc0[e] = gamma[c0] * rsqrtf(v0 + 1e-5f); bi0[e] = beta[c0] - m0 * sc0[e];
            sc1[e] = gamma[c1] * rsqrtf(v1 + 1e-5f); bi1[e] = beta[c1] - m1 * sc1[e];
        }
    }

    // ---- stage phase-0: W half 0 (linear) + B half 0 window ----
    {
#pragma unroll
        for (int i = 0; i < 9; ++i) {
            const int c = tid + i * 256;               // 2304 chunks
            *(bf16x8*)(wl + c * 8) = *(const bf16x8*)(wtb + c * 8);
        }
        const u16* bp = img + ((size_t)(b * 2 + 0) * PS + POFF + w0) * 32;
#pragma unroll
        for (int i = 0; i < 8; ++i) {
            const int c = tid + i * 256;               // 2048 chunks
            bf16x8 v = *(const bf16x8*)(bp + c * 8);
            if (MODE == 1) {
                int pt = w0 + (c >> 2);
                bool val = ((unsigned)pt < (unsigned)NP) && (pt % PRW != PRW - 1);
#pragma unroll
                for (int e = 0; e < 8; ++e) {
                    float t = b2f((u16)v[e]) * sc0[e] + bi0[e];
                    t = (val && t > 0.f) ? t : 0.f;
                    v[e] = (short)f2b(t);
                }
            }
            *(bf16x8*)(bt + c * 8) = v;
        }
    }
    __syncthreads();

    // ---- T14: issue phase-1 W+B global loads NOW (land during phase-0 MFMA) ----
    bf16x8 wpre[9], bpre[8];
#pragma unroll
    for (int i = 0; i < 9; ++i)
        wpre[i] = *(const bf16x8*)(wtb + 18432 + (tid + i * 256) * 8);
    {
        const u16* bp = img + ((size_t)(b * 2 + 1) * PS + POFF + w0) * 32;
#pragma unroll
        for (int i = 0; i < 8; ++i)
            bpre[i] = *(const bf16x8*)(bp + (tid + i * 256) * 8);
    }
    __builtin_amdgcn_sched_barrier(0);   // pin load issue above the k-loop

    // ---- per-fragment LDS slot bases ----
    int lsf[4];
#pragma unroll
    for (int f = 0; f < 4; ++f) {
        const int pix = p0 + wave * 64 + f * 16 + px;
        lsf[f] = pix + pix / HW - w0;    // in [114, 397]
    }

    f32x4 acc[4][4];
#pragma unroll
    for (int f = 0; f < 4; ++f)
#pragma unroll
        for (int m = 0; m < 4; ++m) acc[f][m] = (f32x4)0.f;

    kloop(wl, bt, lsf, kg, px, acc);     // phase 0
    __syncthreads();                     // everyone done reading wl/bt

    // ---- write prefetched phase-1 data to LDS ----
#pragma unroll
    for (int i = 0; i < 9; ++i)
        *(bf16x8*)(wl + (tid + i * 256) * 8) = wpre[i];
#pragma unroll
    for (int i = 0; i < 8; ++i) {
        bf16x8 v = bpre[i];
        if (MODE == 1) {
            const int c = tid + i * 256;
            int pt = w0 + (c >> 2);
            bool val = ((unsigned)pt < (unsigned)NP) && (pt % PRW != PRW - 1);
#pragma unroll
            for (int e = 0; e < 8; ++e) {
                float t = b2f((u16)v[e]) * sc1[e] + bi1[e];
                t = (val && t > 0.f) ? t : 0.f;
                v[e] = (short)f2b(t);
            }
        }
        *(bf16x8*)(bt + (tid + i * 256) * 8) = v;
    }
    __syncthreads();

    kloop(wl, bt, lsf, kg, px, acc);     // phase 1

    // ---- epilogue: unpredicated stores + fused BN batch-stat partials ----
    float s_[4][4], sq[4][4];
#pragma unroll
    for (int m = 0; m < 4; ++m)
#pragma unroll
        for (int q = 0; q < 4; ++q) { s_[m][q] = 0.f; sq[m][q] = 0.f; }

#pragma unroll
    for (int f = 0; f < 4; ++f) {
        const int pix  = p0 + wave * 64 + f * 16 + px;
        const int slot = pix + pix / HW;
#pragma unroll
        for (int m = 0; m < 4; ++m) {
            float v0 = acc[f][m][0], v1 = acc[f][m][1], v2 = acc[f][m][2], v3 = acc[f][m][3];
            s_[m][0] += v0; s_[m][1] += v1; s_[m][2] += v2; s_[m][3] += v3;
            sq[m][0] += v0 * v0; sq[m][1] += v1 * v1;
            sq[m][2] += v2 * v2; sq[m][3] += v3 * v3;
            uint2 pk;
            pk.x = ((unsigned)f2b(v1) << 16) | f2b(v0);
            pk.y = ((unsigned)f2b(v3) << 16) | f2b(v2);
            if (MODE == 0) {
                u16* dst = outp + ((size_t)(b * 2 + (m >> 1)) * PS + POFF + slot) * 32
                                + (m & 1) * 16 + kg * 4;
                *(uint2*)dst = pk;
            } else {
                u16* dst = outp + ((size_t)b * HW2 + pix) * 64 + m * 16 + kg * 4;
                *(uint2*)dst = pk;
            }
        }
    }
#pragma unroll
    for (int off = 1; off < 16; off <<= 1) {
#pragma unroll
        for (int m = 0; m < 4; ++m)
#pragma unroll
            for (int q = 0; q < 4; ++q) {
                s_[m][q] += __shfl_xor(s_[m][q], off);
                sq[m][q] += __shfl_xor(sq[m][q], off);
            }
    }
    __syncthreads();                     // bt reads done; reuse as reduce buffer
    float* red = (float*)bt;             // 4 waves x 128 floats
    if (px == 0) {
#pragma unroll
        for (int m = 0; m < 4; ++m)
#pragma unroll
            for (int q = 0; q < 4; ++q) {
                int c = m * 16 + kg * 4 + q;
                red[wave * 128 + c]      = s_[m][q];
                red[wave * 128 + 64 + c] = sq[m][q];
            }
    }
    __syncthreads();
    if (tid < 128) {
        float t = red[tid] + red[128 + tid] + red[256 + tid] + red[384 + tid];
        atomicAdd(&sums[tid], t);
    }
}

// x f32 NCHW -> padded bf16 half-plane image (interior only)
__global__ __launch_bounds__(256)
void xpad_kernel(const float* __restrict__ x, u16* __restrict__ img)
{
    const int b  = blockIdx.y;
    const int y  = blockIdx.x * 2 + (threadIdx.x >> 7);
    const int px = threadIdx.x & 127;
    if (px >= HW) return;
    const float* xr = x + (size_t)b * CH * HW2 + (size_t)y * HW + px;
#pragma unroll
    for (int cg = 0; cg < 8; ++cg) {
        bf16x8 pk;
#pragma unroll
        for (int j = 0; j < 8; ++j)
            pk[j] = (short)f2b(xr[(size_t)(cg * 8 + j) * HW2]);
        u16* op = img + ((size_t)(b * 2 + (cg >> 2)) * PS + POFF + (size_t)y * PRW + px) * 32
                      + (cg & 3) * 8;
        *(bf16x8*)op = pk;
    }
}

// zero pad slots (512 per half-plane per sample, both images) + stats area
__global__ void border_kernel(u16* __restrict__ a, u16* __restrict__ y1,
                              float* __restrict__ st)
{
    if (blockIdx.x == 256) {
        if (threadIdx.x < 256) st[threadIdx.x] = 0.f;
        return;
    }
    int t = blockIdx.x * 256 + threadIdx.x;      // 0..65535
    u16* buf = (t >= 32768) ? y1 : a;
    int t2 = t & 32767;
    int bh = t2 >> 9;                            // b*2+h (0..63)
    int s  = t2 & 511;
    int slot;
    if (s < POFF)            slot = s;                                   // leading 128
    else if (s < POFF + 273) slot = POFF + NP + (s - POFF);              // trailing 273
    else                     slot = POFF + (s - (POFF + 273)) * PRW + (PRW - 1); // 111 borders
    float4* q = (float4*)(buf + ((size_t)bh * PS + slot) * 32);
#pragma unroll
    for (int i = 0; i < 4; ++i) q[i] = (float4){0.f, 0.f, 0.f, 0.f};
}

// both weights: [b][co][ci][3][3] f32 -> [b][half][tap][kq][co][8ci] bf16
__global__ __launch_bounds__(256)
void repack2_kernel(const float* __restrict__ w1, const float* __restrict__ w2,
                    u16* __restrict__ wt1, u16* __restrict__ wt2)
{
    int i = blockIdx.x * 256 + threadIdx.x;      // 0..2359295
    const int N = NB * 36864;
    const float* w = (i < N) ? w1 : w2;
    u16* wt = (i < N) ? wt1 : wt2;
    int o = (i < N) ? i : i - N;
    int b = o / 36864, r = o - b * 36864;
    int half = r / 18432; r -= half * 18432;
    int tap  = r / 2048;  r -= tap * 2048;
    int kq   = r / 512;   r -= kq * 512;
    int co   = r / 8;
    int ci   = half * 32 + kq * 8 + (r & 7);
    wt[o] = f2b(w[(((size_t)b * 64 + co) * 64 + ci) * 9 + tap]);
}

// out = relu(bn2(y2) + x), NCHW f32 via LDS transpose; y2 compact [b][pix][64]
__global__ __launch_bounds__(256)
void finalize_kernel(const u16* __restrict__ y2, const float* __restrict__ sums,
                     const float* __restrict__ gamma, const float* __restrict__ beta,
                     const float* __restrict__ x, float* __restrict__ out)
{
    __shared__ float lt[64][116];
    __shared__ float sbl[128];
    const int b = blockIdx.y, y = blockIdx.x;
    const int tid = threadIdx.x;
    if (tid < 64) {
        float mean = sums[tid] * (1.f / NPC);
        float var  = sums[64 + tid] * (1.f / NPC) - mean * mean;
        float sc   = gamma[tid] * rsqrtf(var + 1e-5f);
        sbl[tid]      = sc;
        sbl[64 + tid] = beta[tid] - mean * sc;
    }
    __syncthreads();
    const u16* rowp = y2 + ((size_t)b * HW2 + (size_t)y * HW) * 64;
    {
        const int cg = tid & 7;
        float sc[8], bi[8];
#pragma unroll
        for (int e = 0; e < 8; ++e) { sc[e] = sbl[cg * 8 + e]; bi[e] = sbl[64 + cg * 8 + e]; }
        for (int t = tid; t < HW * 8; t += 256) {
            int px = t >> 3;
            bf16x8 v = *(const bf16x8*)(rowp + px * 64 + cg * 8);
#pragma unroll
            for (int e = 0; e < 8; ++e)
                lt[cg * 8 + e][px] = b2f((u16)v[e]) * sc[e] + bi[e];
        }
    }
    __syncthreads();
    {
        const int c = tid >> 2, xg = (tid & 3) * 28;
        size_t base = ((size_t)b * CH + c) * HW2 + (size_t)y * HW + xg;
#pragma unroll
        for (int i = 0; i < 7; ++i) {
            float4 xv = *(const float4*)(x + base + i * 4);
            float4 r;
            r.x = fmaxf(lt[c][xg + i * 4 + 0] + xv.x, 0.f);
            r.y = fmaxf(lt[c][xg + i * 4 + 1] + xv.y, 0.f);
            r.z = fmaxf(lt[c][xg + i * 4 + 2] + xv.z, 0.f);
            r.w = fmaxf(lt[c][xg + i * 4 + 3] + xv.w, 0.f);
            *(float4*)(out + base + i * 4) = r;
        }
    }
}

extern "C" void kernel_launch(void* const* d_in, const int* in_sizes, int n_in,
                              void* d_out, int out_size, void* d_ws, size_t ws_size,
                              hipStream_t stream)
{
    const float* x  = (const float*)d_in[0];
    const float* w1 = (const float*)d_in[1];
    const float* w2 = (const float*)d_in[2];
    const float* g1 = (const float*)d_in[3];
    const float* b1 = (const float*)d_in[4];
    const float* g2 = (const float*)d_in[5];
    const float* b2 = (const float*)d_in[6];
    float* out = (float*)d_out;

    // ws: imgA (padded x, 53.5MB) at 0; y2 compact (51.4MB) OVERLAPS imgA
    // (imgA dead after conv1); stats at +56MB.
    char* ws = (char*)d_ws;
    u16*   imgA = (u16*)ws;
    u16*   y2c  = (u16*)ws;
    float* st   = (float*)(ws + (size_t)(56u << 20));
    float* sums1 = st, *sums2 = st + 128;
    // d_out hosts y1 half-planes + repacked weights; dead before finalize writes.
    char*  oc   = (char*)d_out;
    u16*   y1p  = (u16*)oc;                            // 53.5 MB
    u16*   wt1  = (u16*)(oc + (size_t)(54u << 20));    // 2.25 MB
    u16*   wt2  = (u16*)(oc + (size_t)(58u << 20));    // 2.25 MB

    border_kernel<<<257, 256, 0, stream>>>(imgA, y1p, st);
    xpad_kernel<<<dim3(56, 32), 256, 0, stream>>>(x, imgA);
    repack2_kernel<<<9216, 256, 0, stream>>>(w1, w2, wt1, wt2);

    conv_mfma<0><<<1568, 256, 0, stream>>>(imgA, wt1, y1p, sums1, st, g1, b1);
    conv_mfma<1><<<1568, 256, 0, stream>>>(y1p, wt2, y2c, sums2, sums1, g1, b1);
    finalize_kernel<<<dim3(112, 32), 256, 0, stream>>>(y2c, sums2, g2, b2, x, out);
}